// Round 1
// 878.967 us; speedup vs baseline: 1.0426x; 1.0426x over previous
//
#include <hip/hip_runtime.h>

#define EDGES 200000
#define NATOMS 100000
#define NMOLS 2000
#define H 128
#define MAXNB 15
#define AFD 18
#define INFD 23
#define LROW 136  // LDS A-tile row stride (bf16): +8 pad, 16B-aligned rows, 2-way banks

typedef unsigned short bf16s;
typedef __attribute__((ext_vector_type(8))) short short8;
typedef __attribute__((ext_vector_type(4))) float f32x4;
typedef __attribute__((ext_vector_type(2))) float f32x2;

__device__ inline float bf2f(bf16s u) {
  union { unsigned int i; float f; } c; c.i = ((unsigned int)u) << 16; return c.f;
}
__device__ inline bf16s f2bf(float f) {
  union { float f; unsigned int i; } c; c.f = f;
  unsigned int lsb = (c.i >> 16) & 1u;
  c.i += 0x7fffu + lsb;              // round-to-nearest-even
  return (bf16s)(c.i >> 16);
}
// unpack a u32 holding two packed bf16 [hi|lo] into f32x2 {lo, hi}
__device__ inline f32x2 bfpair(unsigned int u) {
  union { unsigned int i; float f; } lo, hi;
  lo.i = u << 16; hi.i = u & 0xffff0000u;
  return (f32x2){lo.f, hi.f};
}
// relu + pack two f32 into a u32 of two bf16
__device__ inline unsigned int pack2(f32x2 v) {
  return (unsigned int)f2bf(fmaxf(v.x, 0.f)) |
         ((unsigned int)f2bf(fmaxf(v.y, 0.f)) << 16);
}
__device__ inline void load4(const bf16s* p, float v[4]) {
  ushort4 t = *(const ushort4*)p;
  v[0] = bf2f(t.x); v[1] = bf2f(t.y); v[2] = bf2f(t.z); v[3] = bf2f(t.w);
}
__device__ inline void store4(bf16s* p, const float v[4]) {
  ushort4 t; t.x = f2bf(v[0]); t.y = f2bf(v[1]); t.z = f2bf(v[2]); t.w = f2bf(v[3]);
  *(ushort4*)p = t;
}

// ------- one-time: Wt[n][k] = bf16(W[k][n]) for W_h and W_o[AFD:,:] -------
__global__ __launch_bounds__(256) void k_wt(
    const float* __restrict__ Wh, const float* __restrict__ Wo,
    bf16s* __restrict__ wt_h, bf16s* __restrict__ wt_o) {
  const float* S = blockIdx.x ? (Wo + AFD * H) : Wh;
  bf16s* D = blockIdx.x ? wt_o : wt_h;
  for (int i = threadIdx.x; i < H * H; i += 256) {
    int k = i >> 7, n = i & 127;
    D[n * H + k] = f2bf(S[i]);
  }
}

// Two-pass MFMA epilogue: 16x128 @ 128x128 from wave-private LDS tile.
__device__ inline void mfma_two_pass(const bf16s* Aw, const bf16s* __restrict__ Wt,
                                     bf16s* __restrict__ Pout, int ebase, int lane) {
  const int mm = lane & 15;
  const int quad = lane >> 4;
  const bf16s* Wp = Wt + (size_t)mm * H + quad * 8;
  const int rbase = ebase + quad * 4;
#pragma unroll 1
  for (int half = 0; half < 2; ++half) {
    f32x4 acc[4];
#pragma unroll
    for (int i = 0; i < 4; ++i) acc[i] = (f32x4){0.f, 0.f, 0.f, 0.f};
#pragma unroll
    for (int kk = 0; kk < 4; ++kk) {
      short8 af = *(const short8*)&Aw[mm * LROW + quad * 8 + kk * 32];
#pragma unroll
      for (int nt = 0; nt < 4; ++nt) {
        short8 bfr = *(const short8*)(Wp + (size_t)((half * 4 + nt) * 16) * H + kk * 32);
        acc[nt] = __builtin_amdgcn_mfma_f32_16x16x32_bf16(af, bfr, acc[nt], 0, 0, 0);
      }
    }
#pragma unroll
    for (int nt = 0; nt < 4; ++nt) {
#pragma unroll
      for (int i = 0; i < 4; ++i) {
        Pout[(size_t)(rbase + i) * H + (half * 4 + nt) * 16 + mm] = f2bf(acc[nt][i]);
      }
    }
  }
}

// ---- binput = fbonds @ W_i (stored); P1 = relu(binput) @ W_h, wave-private ----
__global__ __launch_bounds__(256) void k_binput_gemm(
    const float* __restrict__ fbonds, const float* __restrict__ Wi,
    const bf16s* __restrict__ wt_h, bf16s* __restrict__ binput,
    bf16s* __restrict__ P1) {
  __shared__ float Wl[INFD * H];
  __shared__ bf16s Am[4][16 * LROW];
  const int tid = threadIdx.x;
  for (int i = tid; i < INFD * H; i += 256) Wl[i] = Wi[i];
  __syncthreads();
  const int wave = tid >> 6;
  const int lane = tid & 63;
  bf16s* Aw = Am[wave];
  const int ebase = (blockIdx.x * 4 + wave) * 16;
  const int sub = lane >> 5;
  const int col = lane & 31;
  for (int r = 0; r < 8; ++r) {
    const int erow = r * 2 + sub;
    const int e = ebase + erow;
    const float* fb = &fbonds[(size_t)e * INFD];
    float acc[4] = {0.f, 0.f, 0.f, 0.f};
#pragma unroll
    for (int k = 0; k < INFD; ++k) {
      float f = fb[k];
      float4 w = *(const float4*)&Wl[k * H + col * 4];
      acc[0] = fmaf(f, w.x, acc[0]); acc[1] = fmaf(f, w.y, acc[1]);
      acc[2] = fmaf(f, w.z, acc[2]); acc[3] = fmaf(f, w.w, acc[3]);
    }
    store4(&binput[(size_t)e * H + col * 4], acc);
    ushort4 mq;
    mq.x = f2bf(fmaxf(acc[0], 0.f)); mq.y = f2bf(fmaxf(acc[1], 0.f));
    mq.z = f2bf(fmaxf(acc[2], 0.f)); mq.w = f2bf(fmaxf(acc[3], 0.f));
    *(ushort4*)&Aw[erow * LROW + col * 4] = mq;
  }
  asm volatile("s_waitcnt lgkmcnt(0)" ::: "memory");
  mfma_two_pass(Aw, wt_h, P1, ebase, lane);
}

// ---- fused depth step: Pout = (relu(binput + sum_j P[bgraph[e][j]])) @ Wt ----
// 16B/lane gathers: 16 lanes cover one 256B message row -> 4 rows per load
// instruction, 4 outer iterations. Doubles in-flight gather bytes per thread
// and halves vmem+address-VALU instruction count vs the 8B/lane version.
// __launch_bounds__(128,4): cap at 128 VGPR so we keep 4 waves/SIMD.
__global__ __launch_bounds__(128, 4) void k_fused(
    const int* __restrict__ bgraph, const bf16s* __restrict__ P,
    const bf16s* __restrict__ binput, const bf16s* __restrict__ Wt,
    bf16s* __restrict__ Pout) {
  __shared__ bf16s Am[2][16 * LROW];
  const int tid = threadIdx.x;
  const int wave = tid >> 6;
  const int lane = tid & 63;
  bf16s* Aw = Am[wave];
  const int ebase = (blockIdx.x * 2 + wave) * 16;

  const int sub = lane >> 4;   // 4 rows per iteration
  const int col = lane & 15;   // 16 lanes x 8 bf16 = 128 cols
#pragma unroll
  for (int it = 0; it < 4; ++it) {
    const int erow = it * 4 + sub;
    const int e = ebase + erow;
    int idx[MAXNB];
#pragma unroll
    for (int j = 0; j < MAXNB; ++j) idx[j] = bgraph[(size_t)e * MAXNB + j];
    uint4 t[MAXNB];
#pragma unroll
    for (int j = 0; j < MAXNB; ++j)
      t[j] = *(const uint4*)&P[(size_t)idx[j] * H + col * 8];
    uint4 bi = *(const uint4*)&binput[(size_t)e * H + col * 8];
    f32x2 acc0 = bfpair(bi.x), acc1 = bfpair(bi.y);
    f32x2 acc2 = bfpair(bi.z), acc3 = bfpair(bi.w);
#pragma unroll
    for (int j = 0; j < MAXNB; ++j) {
      acc0 += bfpair(t[j].x); acc1 += bfpair(t[j].y);
      acc2 += bfpair(t[j].z); acc3 += bfpair(t[j].w);
    }
    uint4 o;
    o.x = pack2(acc0); o.y = pack2(acc1); o.z = pack2(acc2); o.w = pack2(acc3);
    *(uint4*)&Aw[erow * LROW + col * 8] = o;
  }
  asm volatile("s_waitcnt lgkmcnt(0)" ::: "memory");
  mfma_two_pass(Aw, Wt, Pout, ebase, lane);
}

// atom_hiddens = relu(fatoms @ Wo[0:18] + sum_j msgWo[agraph[a][j]] + b_o)
// Same 16B/lane gather restructure: 16 atoms per 256-thread block.
__global__ __launch_bounds__(256, 4) void k_atoms(
    const float* __restrict__ fatoms, const int* __restrict__ agraph,
    const bf16s* __restrict__ msgWo, const float* __restrict__ Wo,
    const float* __restrict__ bo, float* __restrict__ atomh) {
  __shared__ float Wl[AFD * H];
  const int tid = threadIdx.x;
  for (int i = tid; i < AFD * H; i += 256) Wl[i] = Wo[i];
  __syncthreads();
  const int col = tid & 15;
  const int a = blockIdx.x * 16 + (tid >> 4);
  int idx[MAXNB];
#pragma unroll
  for (int j = 0; j < MAXNB; ++j) idx[j] = agraph[(size_t)a * MAXNB + j];
  uint4 t[MAXNB];
#pragma unroll
  for (int j = 0; j < MAXNB; ++j)
    t[j] = *(const uint4*)&msgWo[(size_t)idx[j] * H + col * 8];
  float4 b0 = ((const float4*)bo)[col * 2];
  float4 b1 = ((const float4*)bo)[col * 2 + 1];
  f32x2 acc0 = (f32x2){b0.x, b0.y}, acc1 = (f32x2){b0.z, b0.w};
  f32x2 acc2 = (f32x2){b1.x, b1.y}, acc3 = (f32x2){b1.z, b1.w};
#pragma unroll
  for (int k = 0; k < AFD; ++k) {
    float f = fatoms[(size_t)a * AFD + k];
    float4 w0 = *(const float4*)&Wl[k * H + col * 8];
    float4 w1 = *(const float4*)&Wl[k * H + col * 8 + 4];
    acc0.x = fmaf(f, w0.x, acc0.x); acc0.y = fmaf(f, w0.y, acc0.y);
    acc1.x = fmaf(f, w0.z, acc1.x); acc1.y = fmaf(f, w0.w, acc1.y);
    acc2.x = fmaf(f, w1.x, acc2.x); acc2.y = fmaf(f, w1.y, acc2.y);
    acc3.x = fmaf(f, w1.z, acc3.x); acc3.y = fmaf(f, w1.w, acc3.y);
  }
#pragma unroll
  for (int j = 0; j < MAXNB; ++j) {
    acc0 += bfpair(t[j].x); acc1 += bfpair(t[j].y);
    acc2 += bfpair(t[j].z); acc3 += bfpair(t[j].w);
  }
  float4 r0 = make_float4(fmaxf(acc0.x, 0.f), fmaxf(acc0.y, 0.f),
                          fmaxf(acc1.x, 0.f), fmaxf(acc1.y, 0.f));
  float4 r1 = make_float4(fmaxf(acc2.x, 0.f), fmaxf(acc2.y, 0.f),
                          fmaxf(acc3.x, 0.f), fmaxf(acc3.y, 0.f));
  *(float4*)&atomh[(size_t)a * H + col * 8] = r0;
  *(float4*)&atomh[(size_t)a * H + col * 8 + 4] = r1;
}

// ---------------- segment mean pool ----------------
__global__ void k_pool(const float* __restrict__ atomh,
                       const int* __restrict__ sstart, const int* __restrict__ slen,
                       float* __restrict__ out) {
  const int m = blockIdx.x;
  const int c = threadIdx.x;
  const int s = sstart[m];
  const int L = slen[m];
  float sum = 0.f;
  for (int i = 0; i < L; ++i) sum += atomh[(size_t)(s + i) * H + c];
  out[m * H + c] = sum / (float)L;
}

extern "C" void kernel_launch(void* const* d_in, const int* in_sizes, int n_in,
                              void* d_out, int out_size, void* d_ws, size_t ws_size,
                              hipStream_t stream) {
  const float* fatoms = (const float*)d_in[0];
  const float* fbonds = (const float*)d_in[1];
  const int* agraph = (const int*)d_in[2];
  const int* bgraph = (const int*)d_in[3];
  const int* sstart = (const int*)d_in[4];
  const int* slen = (const int*)d_in[5];
  const float* Wi = (const float*)d_in[6];
  const float* Wh = (const float*)d_in[7];
  const float* Wo = (const float*)d_in[8];
  const float* bo = (const float*)d_in[9];
  float* out = (float*)d_out;

  const size_t EH = (size_t)EDGES * H;
  bf16s* B0 = (bf16s*)d_ws;      // binput [E,H] bf16, 51.2 MB
  bf16s* B1 = B0 + EH;           // ping
  bf16s* B2 = B1 + EH;           // pong
  float* atomh = (float*)B0;     // overlays binput (dead after last fused step)
  bf16s* wt_h = (bf16s*)d_out;   // stashed in d_out; k_pool overwrites later
  bf16s* wt_o = wt_h + H * H;

  k_wt<<<2, 256, 0, stream>>>(Wh, Wo, wt_h, wt_o);
  k_binput_gemm<<<EDGES / 64, 256, 0, stream>>>(fbonds, Wi, wt_h, B0, B1);  // P1
  k_fused<<<EDGES / 32, 128, 0, stream>>>(bgraph, B1, B0, wt_h, B2);    // P2
  k_fused<<<EDGES / 32, 128, 0, stream>>>(bgraph, B2, B0, wt_h, B1);    // P3
  k_fused<<<EDGES / 32, 128, 0, stream>>>(bgraph, B1, B0, wt_h, B2);    // P4
  k_fused<<<EDGES / 32, 128, 0, stream>>>(bgraph, B2, B0, wt_h, B1);    // P5
  k_fused<<<EDGES / 32, 128, 0, stream>>>(bgraph, B1, B0, wt_o, B2);    // P6o
  k_atoms<<<NATOMS / 16, 256, 0, stream>>>(fatoms, agraph, B2, Wo, bo, atomh);
  k_pool<<<NMOLS, H, 0, stream>>>(atomh, sstart, slen, out);
}